// Round 2
// baseline (38563.547 us; speedup 1.0000x reference)
//
#include <hip/hip_runtime.h>

// FFJORD density on MI355X (gfx950). B=65536 rows, DIM=128, HID=512, 32 RK4 steps x 4 evals.
// Round 2: ws_size-respecting adaptive chunking (round-1 crash = workspace overflow -> GPU
// page fault). Per-stage MFMA bf16 GEMM kernels with fused epilogues:
//   K1: h1 = tanh(zs @ W1z + t*w1t + b1)           (zs = bf16 stage input)
//   K2: h2 = tanh(h1 @ W2 + b2)
//   K3: f  = h2 @ W3 + b3; acc += wrk*f; zs = bf16(z + c_next*f)  (or z += acc at s3)
//   K4: g1 = ((g3*(1-h2^2)) @ W2^T) * (1-h1^2)     (g2 built on the fly in staging)
//   K5: vJ = g1 @ W1z^T; lp-acc -= wrk * rowsum(vJ*v)
// g3 = v @ W3^T computed once per chunk. Weights packed bf16 [k>>3][n][k&7] once per call.

#define DIMV 128
#define HIDV 512

typedef float  floatx4 __attribute__((ext_vector_type(4)));
typedef short  short8  __attribute__((ext_vector_type(8)));

static __device__ __forceinline__ unsigned short f2bf(float x) {
    union { float f; unsigned int u; } c; c.f = x;
    unsigned int u = c.u;
    u += 0x7FFFu + ((u >> 16) & 1u);   // round-to-nearest-even
    return (unsigned short)(u >> 16);
}
static __device__ __forceinline__ float bf2f(unsigned short h) {
    union { unsigned int u; float f; } c; c.u = ((unsigned int)h) << 16;
    return c.f;
}
static __device__ __forceinline__ float fast_tanh(float x) {
    x = fminf(8.0f, fmaxf(-8.0f, x));
    float e = exp2f(x * 2.8853900817779268f);            // exp(2x)
    return (e - 1.0f) * __builtin_amdgcn_rcpf(e + 1.0f); // (e-1)/(e+1)
}

// ---- weight packing: dst[(k>>3)*N*8 + n*8 + (k&7)] = bf16(W[k][n]) ------------
__global__ void pack_kernel(const float* __restrict__ src, unsigned short* __restrict__ dst,
                            int K, int N, int ld, int transpose) {
    int i = blockIdx.x * 256 + threadIdx.x;
    if (i >= K * N) return;
    int j  = i & 7;
    int n  = (i >> 3) % N;
    int k8 = (i >> 3) / N;
    int k  = k8 * 8 + j;
    float v = transpose ? src[n * ld + k] : src[k * ld + n];
    dst[i] = f2bf(v);
}

// ---- per-chunk init: z = x (fp32), zs = bf16(x), lp = 0 -----------------------
__global__ void init_k(const float* __restrict__ x, float* __restrict__ z,
                       unsigned short* __restrict__ zs, float* __restrict__ lp,
                       int n, int nrows) {
    int i = blockIdx.x * 256 + threadIdx.x;
    if (i < n) { float val = x[i]; z[i] = val; zs[i] = f2bf(val); }
    if (i < nrows) lp[i] = 0.0f;
}

#define PROD_BF16 0
#define PROD_V    1
#define PROD_G2   2
#define EPI_H1   0
#define EPI_G3   1
#define EPI_H2   2
#define EPI_G1   3
#define EPI_F    4

struct GArgs {
    const float* z;            // fp32 base state [C,128]
    const float* v;            // fp32 probe (chunk ptr) [C,128]
    const unsigned short* A;   // bf16 A input
    const unsigned short* A2;  // bf16 second input (g3 for PROD_G2)
    const unsigned short* Wp;  // packed bf16 weights
    const float* bias;
    const float* w1t;          // W1 row 128 (t coefficients)
    unsigned short* out0;      // bf16 output (h1/g3/h2/g1-in-place)
    unsigned short* zs_out;    // bf16 next-stage input
    float* z_out;              // fp32 state out (aliases z)
    float* accf;
    float* accd;
    float* lp;
    float t, cnext, wrk;
    int s0, s3;
};

// Tile: 128 rows x (NFRAG*64) cols per WG; 4 waves; wave = 8 m-frags x NFRAG n-frags.
// LDS A-chunk: 128 rows x 64 k, stride 72 bf16 (144B: 16B-aligned, 2-way bank alias only).
template<int KDIM, int NDIM, int NFRAG, int PROD, int EPI>
__global__ __launch_bounds__(256, 2) void gemm_k(GArgs p) {
    __shared__ __align__(16) unsigned short As[128 * 72];
    const int tid  = threadIdx.x;
    const int wave = tid >> 6, lane = tid & 63;
    const int quad = lane >> 4, l16 = lane & 15;
    const int row0 = blockIdx.x * 128;
    const int colw = blockIdx.y * (NFRAG * 64) + wave * (NFRAG * 16);

    floatx4 acc[8][NFRAG];
    #pragma unroll
    for (int m = 0; m < 8; ++m)
        #pragma unroll
        for (int f = 0; f < NFRAG; ++f) {
            floatx4 zz = {0.f, 0.f, 0.f, 0.f};
            acc[m][f] = zz;
        }

    for (int k0 = 0; k0 < KDIM; k0 += 64) {
        __syncthreads();
        {   // ---- stage A chunk: 128 rows x 64 k into LDS ----
            const int r  = tid >> 3;
            const int cc = (tid & 7) << 3;
            #pragma unroll
            for (int i = 0; i < 4; ++i) {
                const int rr = r + (i << 5);
                const size_t base = (size_t)(row0 + rr) * KDIM + k0 + cc;
                if constexpr (PROD == PROD_BF16) {
                    const short8 val = *reinterpret_cast<const short8*>(&p.A[base]);
                    *reinterpret_cast<short8*>(&As[rr * 72 + cc]) = val;
                } else if constexpr (PROD == PROD_V) {
                    float vals[8];
                    *(float4*)&vals[0] = *(const float4*)&p.v[base];
                    *(float4*)&vals[4] = *(const float4*)&p.v[base + 4];
                    short8 sv;
                    #pragma unroll
                    for (int j = 0; j < 8; ++j) sv[j] = (short)f2bf(vals[j]);
                    *reinterpret_cast<short8*>(&As[rr * 72 + cc]) = sv;
                } else { // PROD_G2: g2 = g3 * (1 - h2^2) built on the fly
                    const short8 hv = *reinterpret_cast<const short8*>(&p.A[base]);
                    const short8 gv = *reinterpret_cast<const short8*>(&p.A2[base]);
                    short8 sv;
                    #pragma unroll
                    for (int j = 0; j < 8; ++j) {
                        float h = bf2f((unsigned short)hv[j]);
                        float g = bf2f((unsigned short)gv[j]);
                        sv[j] = (short)f2bf(g * (1.0f - h * h));
                    }
                    *reinterpret_cast<short8*>(&As[rr * 72 + cc]) = sv;
                }
            }
        }
        __syncthreads();
        // ---- compute: 2 k-tiles of 32 ----
        #pragma unroll
        for (int kt = 0; kt < 2; ++kt) {
            const int k8 = (k0 >> 3) + (kt << 2) + quad;
            short8 b[NFRAG];
            #pragma unroll
            for (int f = 0; f < NFRAG; ++f)
                b[f] = *reinterpret_cast<const short8*>(
                    &p.Wp[((size_t)k8 * NDIM + colw + (f << 4) + l16) << 3]);
            #pragma unroll
            for (int m = 0; m < 8; ++m) {
                const short8 a = *reinterpret_cast<const short8*>(
                    &As[(m * 16 + l16) * 72 + (kt << 5) + (quad << 3)]);
                #pragma unroll
                for (int f = 0; f < NFRAG; ++f)
                    acc[m][f] = __builtin_amdgcn_mfma_f32_16x16x32_bf16(a, b[f], acc[m][f], 0, 0, 0);
            }
        }
    }

    // ---- epilogue: D row = quad*4+reg, col = lane&15 ----
    #pragma unroll
    for (int m = 0; m < 8; ++m) {
        #pragma unroll
        for (int f = 0; f < NFRAG; ++f) {
            const int col = colw + (f << 4) + l16;
            float bias = 0.0f;
            if constexpr (EPI == EPI_H1) bias = p.bias[col] + p.t * p.w1t[col];
            else if constexpr (EPI == EPI_H2 || EPI == EPI_F) bias = p.bias[col];
            #pragma unroll
            for (int r = 0; r < 4; ++r) {
                const int row = row0 + m * 16 + quad * 4 + r;
                const size_t idxN = (size_t)row * NDIM + col;
                float x = acc[m][f][r] + bias;
                if constexpr (EPI == EPI_H1) {
                    p.out0[idxN] = f2bf(fast_tanh(x));
                } else if constexpr (EPI == EPI_G3) {
                    p.out0[idxN] = f2bf(x);
                } else if constexpr (EPI == EPI_H2) {
                    p.out0[idxN] = f2bf(fast_tanh(x));
                } else if constexpr (EPI == EPI_G1) {
                    float h1v = bf2f(p.out0[idxN]);              // read h1
                    p.out0[idxN] = f2bf(x * (1.0f - h1v * h1v)); // write g1 in place
                } else if constexpr (EPI == EPI_F) {
                    float a = p.wrk * x + (p.s0 ? 0.0f : p.accf[idxN]);
                    if (p.s3) {
                        float zn = p.z[idxN] + a;                // z += dt/6 * sum(k)
                        p.z_out[idxN]  = zn;
                        p.zs_out[idxN] = f2bf(zn);               // next step s0 input
                    } else {
                        p.accf[idxN]   = a;
                        p.zs_out[idxN] = f2bf(p.z[idxN] + p.cnext * x); // next stage input
                    }
                }
            }
        }
    }
}

// ---- K5: vJ = g1 @ W1z^T, div = rowsum(vJ * v). Wave owns 32 rows, all 128 cols.
__global__ __launch_bounds__(256, 2) void gemm_div_k(GArgs p) {
    __shared__ __align__(16) unsigned short As[128 * 72];
    const int tid  = threadIdx.x;
    const int wave = tid >> 6, lane = tid & 63;
    const int quad = lane >> 4, l16 = lane & 15;
    const int row0 = blockIdx.x * 128;
    constexpr int KDIM = 512, NDIM = 128;

    floatx4 acc[2][8];
    #pragma unroll
    for (int m = 0; m < 2; ++m)
        #pragma unroll
        for (int f = 0; f < 8; ++f) {
            floatx4 zz = {0.f, 0.f, 0.f, 0.f};
            acc[m][f] = zz;
        }

    for (int k0 = 0; k0 < KDIM; k0 += 64) {
        __syncthreads();
        {
            const int r  = tid >> 3;
            const int cc = (tid & 7) << 3;
            #pragma unroll
            for (int i = 0; i < 4; ++i) {
                const int rr = r + (i << 5);
                const short8 val = *reinterpret_cast<const short8*>(
                    &p.A[(size_t)(row0 + rr) * KDIM + k0 + cc]);
                *reinterpret_cast<short8*>(&As[rr * 72 + cc]) = val;
            }
        }
        __syncthreads();
        #pragma unroll
        for (int kt = 0; kt < 2; ++kt) {
            const int k8 = (k0 >> 3) + (kt << 2) + quad;
            short8 b[8];
            #pragma unroll
            for (int f = 0; f < 8; ++f)
                b[f] = *reinterpret_cast<const short8*>(
                    &p.Wp[((size_t)k8 * NDIM + (f << 4) + l16) << 3]);
            #pragma unroll
            for (int m = 0; m < 2; ++m) {
                const short8 a = *reinterpret_cast<const short8*>(
                    &As[((wave << 5) + m * 16 + l16) * 72 + (kt << 5) + (quad << 3)]);
                #pragma unroll
                for (int f = 0; f < 8; ++f)
                    acc[m][f] = __builtin_amdgcn_mfma_f32_16x16x32_bf16(a, b[f], acc[m][f], 0, 0, 0);
            }
        }
    }

    #pragma unroll
    for (int m = 0; m < 2; ++m) {
        #pragma unroll
        for (int r = 0; r < 4; ++r) {
            const int row = row0 + (wave << 5) + m * 16 + quad * 4 + r;
            float part = 0.0f;
            #pragma unroll
            for (int f = 0; f < 8; ++f)
                part += acc[m][f][r] * p.v[(size_t)row * 128 + (f << 4) + l16];
            part += __shfl_xor(part, 1);
            part += __shfl_xor(part, 2);
            part += __shfl_xor(part, 4);
            part += __shfl_xor(part, 8);
            if (l16 == 0) {
                float a = p.wrk * (-part) + (p.s0 ? 0.0f : p.accd[row]);
                if (p.s3) p.lp[row] += a;
                else      p.accd[row] = a;
            }
        }
    }
}

// out[b] = lp[b] - 0.5*||z||^2 - 0.5*128*log(2*pi)
__global__ void final_k(const float* __restrict__ z, const float* __restrict__ lp,
                        float* __restrict__ out) {
    const int tid = threadIdx.x;
    const int row = blockIdx.x * 16 + (tid >> 4);
    const int l16 = tid & 15;
    const float4* zr = (const float4*)&z[(size_t)row * 128 + (l16 << 3)];
    float4 a = zr[0], b = zr[1];
    float s = a.x*a.x + a.y*a.y + a.z*a.z + a.w*a.w
            + b.x*b.x + b.y*b.y + b.z*b.z + b.w*b.w;
    s += __shfl_xor(s, 1);
    s += __shfl_xor(s, 2);
    s += __shfl_xor(s, 4);
    s += __shfl_xor(s, 8);
    if (l16 == 0) out[row] = lp[row] - 0.5f * s - 117.6241322501981f;
}

extern "C" void kernel_launch(void* const* d_in, const int* in_sizes, int n_in,
                              void* d_out, int out_size, void* d_ws, size_t ws_size,
                              hipStream_t stream) {
    (void)n_in; (void)out_size;
    const float* x  = (const float*)d_in[0];
    const float* v  = (const float*)d_in[1];
    const float* W1 = (const float*)d_in[2];
    const float* b1 = (const float*)d_in[3];
    const float* W2 = (const float*)d_in[4];
    const float* b2 = (const float*)d_in[5];
    const float* W3 = (const float*)d_in[6];
    const float* b3 = (const float*)d_in[7];
    float* out = (float*)d_out;
    const int B = in_sizes[0] / DIMV;   // 65536

    auto al = [](size_t s) { return (s + 255) & ~(size_t)255; };
    auto need_for = [&](size_t C) {
        size_t s = 0;
        s += al(C * DIMV * 4);       // z
        s += al(C * DIMV * 4);       // accf
        s += al(C * DIMV * 2);       // zs
        s += al(C * 4);              // lp
        s += al(C * 4);              // accd
        s += al(C * HIDV * 2) * 3;   // h1 (g1 in place), h2, g3
        s += al(128 * 512 * 2) * 4 + al(512 * 512 * 2) * 2; // packed weights
        return s;
    };
    // Largest power-of-two chunk (<=32768 rows: keeps working set inside 256MB L3)
    // that fits ws_size. Round-1 crash root cause: unchecked workspace overflow.
    size_t C = 32768;
    while (C > 1024 && need_for(C) > ws_size) C >>= 1;
    if (need_for(C) > ws_size) return;  // cannot run safely in this workspace

    char* w = (char*)d_ws;
    auto alloc = [&](size_t bytes) { char* p = w; w += al(bytes); return p; };
    float* z    = (float*)alloc(C * DIMV * 4);
    float* accf = (float*)alloc(C * DIMV * 4);
    unsigned short* zs = (unsigned short*)alloc(C * DIMV * 2);
    float* lp   = (float*)alloc(C * 4);
    float* accd = (float*)alloc(C * 4);
    unsigned short* h1 = (unsigned short*)alloc(C * HIDV * 2); // h1, then g1 in place
    unsigned short* h2 = (unsigned short*)alloc(C * HIDV * 2);
    unsigned short* g3 = (unsigned short*)alloc(C * HIDV * 2);
    unsigned short* W1zp  = (unsigned short*)alloc(128 * 512 * 2);
    unsigned short* W3p   = (unsigned short*)alloc(512 * 128 * 2);
    unsigned short* W1zTp = (unsigned short*)alloc(512 * 128 * 2);
    unsigned short* W3Tp  = (unsigned short*)alloc(128 * 512 * 2);
    unsigned short* W2p   = (unsigned short*)alloc(512 * 512 * 2);
    unsigned short* W2Tp  = (unsigned short*)alloc(512 * 512 * 2);

    auto pack = [&](const float* src, unsigned short* dst, int K, int N, int ld, int tr) {
        pack_kernel<<<dim3((K * N + 255) / 256), dim3(256), 0, stream>>>(src, dst, K, N, ld, tr);
    };
    pack(W1, W1zp,  128, 512, 512, 0);
    pack(W2, W2p,   512, 512, 512, 0);
    pack(W3, W3p,   512, 128, 128, 0);
    pack(W2, W2Tp,  512, 512, 512, 1);
    pack(W1, W1zTp, 512, 128, 512, 1);
    pack(W3, W3Tp,  128, 512, 128, 1);

    const float dt = 1.0f / 32.0f;
    const float cs[4]  = {0.0f, 0.5f * dt, 0.5f * dt, dt};
    const float wr4[4] = {dt / 6.0f, dt / 3.0f, dt / 3.0f, dt / 6.0f};
    const int GM = (int)C / 128;

    for (int c0 = 0; c0 < B; c0 += (int)C) {
        const float* xc = x + (size_t)c0 * DIMV;
        const float* vc = v + (size_t)c0 * DIMV;

        init_k<<<dim3(((int)C * DIMV + 255) / 256), 256, 0, stream>>>(
            xc, z, zs, lp, (int)C * DIMV, (int)C);

        {   // g3 = v @ W3^T  (once per chunk)
            GArgs p{};
            p.v = vc; p.Wp = W3Tp; p.out0 = g3;
            gemm_k<128, 512, 4, PROD_V, EPI_G3><<<dim3(GM, 2), 256, 0, stream>>>(p);
        }

        for (int step = 0; step < 32; ++step) {
            const float t0 = (float)step * dt;
            for (int s = 0; s < 4; ++s) {
                GArgs p{};
                p.t = t0 + cs[s]; p.wrk = wr4[s];
                p.cnext = (s < 3) ? cs[s + 1] : 0.0f;
                p.s0 = (s == 0); p.s3 = (s == 3);
                p.z = z; p.v = vc;
                p.accf = accf; p.accd = accd; p.lp = lp;

                // K1: h1 = tanh(zs @ W1z + t*w1t + b1)
                p.A = zs; p.Wp = W1zp; p.bias = b1; p.w1t = W1 + 128 * 512; p.out0 = h1;
                gemm_k<128, 512, 4, PROD_BF16, EPI_H1><<<dim3(GM, 2), 256, 0, stream>>>(p);

                // K2: h2 = tanh(h1 @ W2 + b2)
                p.A = h1; p.Wp = W2p; p.bias = b2; p.out0 = h2;
                gemm_k<512, 512, 4, PROD_BF16, EPI_H2><<<dim3(GM, 2), 256, 0, stream>>>(p);

                // K3: f = h2 @ W3 + b3; acc += wrk*f; zs = bf16(z + cnext*f) (s3: z += acc)
                p.A = h2; p.Wp = W3p; p.bias = b3;
                p.z_out = z; p.zs_out = zs;
                gemm_k<512, 128, 2, PROD_BF16, EPI_F><<<dim3(GM, 1), 256, 0, stream>>>(p);

                // K4: g1 = ((g3*(1-h2^2)) @ W2^T) * (1-h1^2)   [g2 on the fly; g1 over h1]
                p.A = h2; p.A2 = g3; p.Wp = W2Tp; p.out0 = h1;
                gemm_k<512, 512, 4, PROD_G2, EPI_G1><<<dim3(GM, 2), 256, 0, stream>>>(p);

                // K5: vJ = g1 @ W1z^T; div = rowsum(vJ*v); accd (+)= wrk*(-div); s3: lp += accd
                p.A = h1; p.Wp = W1zTp;
                gemm_div_k<<<dim3(GM), 256, 0, stream>>>(p);
            }
        }

        final_k<<<dim3((int)C / 16), 256, 0, stream>>>(z, lp, out + c0);
    }
}